// Round 23
// baseline (24.124 us; speedup 1.0000x reference)
//
#include <hip/hip_runtime.h>
#include <math.h>

// Problem constants (match reference)
#define HWPX (512*512)      // pixels per batch
#define NB 2                // batches
#define NL 512              // EH*EW light directions
#define NLS 480             // shadeable lights (phi=0 row: coeff 0)
#define NPAIR 240
#define GPAIR 60
#define NBLK 2048
// radiance-field table (lat-long, lights' (phi,theta) parametrization), 64x128
#define NPH 64
#define NTH 128
#define ROWS (NPH + 1)                 // 65
#define COLS (NTH + 1)                 // 129 (theta wrap duplicate)
#define NODES (ROWS * COLS)            // 8385 per batch
#define BPB_BUILD 132                  // ceil(NODES/64) : 64 nodes per block
#define NBUILD (NB * BPB_BUILD)        // 264 build blocks
#define NODESTRIDE (BPB_BUILD * 64)    // 8448
constexpr float PI_F   = 3.14159265358979323846f;
constexpr float TWO_PI = 6.28318530717958647692f;
constexpr float INV_SQRT2 = 0.70710678118654752f;

typedef float f2 __attribute__((ext_vector_type(2)));

// ws layout (bytes), main path:
//   [256]    float blockmax[2048]            (8 KB)
//   [16384]  float4 table[2][NODESTRIDE]     (~270 KB unnormalized radiance field)
// Fallback path (ws too small): scale@0, tabq@256, blockmax@24576 (R13 exact).
//
// R22: revert to R20's proven 2-dispatch structure (coop fuse was timing-null,
// R21) + fix the max path's LDS bank conflicts found by R21's profile
// (1.8M SQ_LDS_BANK_CONFLICT): candidate-max gathers were float4 (4 banks/lane
// x 64 random lanes = 8-way avg conflict). Half-vectors now SoA (shx/shy/shz,
// b32 reads -> ~2-way = free per m136).

// fast acos (A&S 4.4.45), |err| <= 6.7e-5 rad
__device__ __forceinline__ float acos_fast(float x) {
    float ax = fabsf(x);
    float r = sqrtf(fmaxf(1.0f - ax, 0.0f)) *
              (1.5707288f + ax * (-0.2121144f + ax * (0.0742610f - ax * 0.0187293f)));
    return x >= 0.0f ? r : PI_F - r;
}

// fast atan2(y,x), |err| ~1e-5 rad
__device__ __forceinline__ float atan2_fast(float y, float x) {
    float ay = fabsf(y), ax = fabsf(x);
    float mx = fmaxf(ay, ax), mn = fminf(ay, ax);
    float a = mn / fmaxf(mx, 1e-30f);
    float s = a * a;
    float r = a * (0.9998660f + s * (-0.3302995f + s * (0.1801410f +
              s * (-0.0851330f + s * 0.0208351f))));
    if (ay > ax) r = 1.5707963f - r;
    if (x < 0.0f) r = PI_F - r;
    return y < 0.0f ? -r : r;
}

// unit half-vector (and sin(phi)) for light index m in [0,512)
__device__ __forceinline__ void light_h(int m, float& hx, float& hy, float& hz, float& sp) {
    int p = m >> 5, t = m & 31;
    float phi = (float)p * (PI_F / 16.0f);
    float th  = (float)t * (TWO_PI / 32.0f);
    float spv, cpv, stv, ctv;
    sincosf(phi, &spv, &cpv);
    sincosf(th, &stv, &ctv);
    float x = stv * spv, y = cpv, z = 1.0f - ctv * spv;
    float inv = rsqrtf(x * x + y * y + z * z);
    hx = x * inv; hy = y * inv; hz = z * inv; sp = spv;
}

__device__ __forceinline__ void load_normal(const float* __restrict__ normal, size_t pix,
                                            float& nx, float& ny, float& nz) {
    const float* p = normal + pix * 3;
    float c0 = p[0], c1 = p[1], c2 = p[2];
    float x = (c2 - 0.5f) * 2.0f;
    float y = (c1 - 0.5f) * 2.0f;
    float z = (c0 - 0.5f) * 2.0f;
    float d2 = x * x + y * y + z * z;
    float inv = d2 > 0.0f ? rsqrtf(d2) : 0.0f;
    nx = x * inv; ny = y * inv; nz = z * inv;
}

__device__ __forceinline__ float pow64(float r) {
    float r2  = r * r;
    float r4  = r2 * r2;
    float r8  = r4 * r4;
    float r16 = r8 * r8;
    float r32 = r16 * r16;
    return r32 * r32;
}

// ---------- Pass 1: heterogeneous — table build OR candidate max ----------
__global__ __launch_bounds__(256) void k_pre(const float* __restrict__ env,
                                             const float* __restrict__ normal,
                                             float4* __restrict__ table,
                                             float* __restrict__ blockmax) {
    __shared__ float smem[NPAIR * 12];             // 11.25 KB (build: tabL / max: SoA hvec)
    int tid = threadIdx.x, bid = blockIdx.x;

    if (bid < NBUILD) {
        // ======== BUILD path: 64 nodes/block, 1 node/thread ========
        float* tabL = smem;
        __shared__ float smerge[3 * 64 * 5];       // partials, odd stride 5
        int b = bid / BPB_BUILD;
        int blk = bid % BPB_BUILD;
        int g = tid >> 6;                          // light quarter
        int li = tid & 63;                         // node lane
        int node = blk * 64 + li;                  // may overrun NODES (write guarded)

        // in-block light table generation (<=2 lights per thread)
        for (int ms = tid; ms < NLS; ms += 256) {
            int m = ms + 32;                       // skip phi=0 row
            float hx, hy, hz, sp;
            light_h(m, hx, hy, hz, sp);
            float c = sp * (1.0f / 60.0f);
            const float* e = env + ((size_t)(b * NL + m)) * 3;
            float* dst = tabL + (ms >> 1) * 12 + (ms & 1);
            dst[0]  = hx;
            dst[2]  = hy;
            dst[4]  = hz;
            dst[6]  = e[0] * c;
            dst[8]  = e[1] * c;
            dst[10] = e[2] * c;
        }

        // this thread's grid direction (splat into f2 lanes = light-pair lanes)
        int i = node / COLS;
        int j = node - i * COLS;
        float phi = (float)i * (PI_F / (float)NPH);
        float th  = (float)j * (TWO_PI / (float)NTH);
        float spv, cpv, stv, ctv;
        sincosf(phi, &spv, &cpv);
        sincosf(th, &stv, &ctv);
        f2 nx2 = f2{stv * spv, stv * spv};
        f2 ny2 = f2{cpv, cpv};
        f2 nz2 = f2{-ctv * spv, -ctv * spv};
        __syncthreads();

        f2 a0 = f2{0, 0}, a1 = f2{0, 0}, a2 = f2{0, 0};
        const float4* Tg = reinterpret_cast<const float4*>(tabL) + (size_t)g * (GPAIR * 3);
        #pragma unroll 4
        for (int jj = 0; jj < GPAIR; ++jj) {
            float4 A = Tg[jj * 3 + 0];             // {hx0,hx1,hy0,hy1}  (wave-uniform)
            float4 B = Tg[jj * 3 + 1];             // {hz0,hz1,e00,e01}
            float4 C = Tg[jj * 3 + 2];             // {e10,e11,e20,e21}
            f2 hx2 = {A.x, A.y}, hy2 = {A.z, A.w}, hz2 = {B.x, B.y};
            f2 e02 = {B.z, B.w}, e12 = {C.x, C.y}, e22 = {C.z, C.w};
            f2 s = __builtin_elementwise_fma(nx2, hx2,
                   __builtin_elementwise_fma(ny2, hy2, nz2 * hz2));
            float sx = fmaxf(s.x, 0.0f);
            float sy = fmaxf(s.y, 0.0f);
            f2 r = {sx, sy};
            f2 r2  = r * r;
            f2 r4  = r2 * r2;
            f2 r8  = r4 * r4;
            f2 r16 = r8 * r8;
            f2 r32 = r16 * r16;
            f2 r64 = r32 * r32;
            a0 = __builtin_elementwise_fma(r64, e02, a0);
            a1 = __builtin_elementwise_fma(r64, e12, a1);
            a2 = __builtin_elementwise_fma(r64, e22, a2);
        }

        float b0 = a0.x + a0.y;
        float b1 = a1.x + a1.y;
        float b2 = a2.x + a2.y;

        if (g > 0) {
            float* dst = smerge + (size_t)(g - 1) * (64 * 5) + li * 5;
            dst[0] = b0; dst[1] = b1; dst[2] = b2;
        }
        __syncthreads();

        if (g == 0) {
            #pragma unroll
            for (int gg = 0; gg < 3; ++gg) {
                const float* src = smerge + (size_t)gg * (64 * 5) + li * 5;
                b0 += src[0]; b1 += src[1]; b2 += src[2];
            }
            if (node < NODES) {
                float4 v; v.x = b0; v.y = b1; v.z = b2; v.w = 0.0f;
                table[(size_t)b * NODESTRIDE + node] = v;
            }
        }
    } else {
        // ======== MAX path (SoA hvec: b32 gathers, ~2-way banks = free) ========
        float* shx = smem;                         // [512]
        float* shy = smem + 512;
        float* shz = smem + 1024;
        __shared__ float swmax[4];
        int mbid = bid - NBUILD;                   // 0..NBLK-1
        int b = mbid >> 10;
        int pix_in_b = (mbid & 1023) * 256 + tid;

        for (int m = tid; m < NL; m += 256) {
            float hx, hy, hz, sp;
            light_h(m, hx, hy, hz, sp);
            shx[m] = hx; shy[m] = hy; shz[m] = hz;
        }

        float nx, ny, nz;
        load_normal(normal, (size_t)b * HWPX + pix_in_b, nx, ny, nz);
        __syncthreads();

        // invert: l = 2*nz*n - v (reflection about h=n); light grid is 16x32
        float lx = 2.0f * nz * nx;
        float ly = 2.0f * nz * ny;
        float lz = 2.0f * nz * nz - 1.0f;
        float fi = acos_fast(fminf(fmaxf(ly, -1.0f), 1.0f)) * (16.0f / PI_F);
        float th = atan2_fast(lx, -lz);
        float tt = th * (0.5f / PI_F);
        float fj = (tt - floorf(tt)) * 32.0f;
        int i0 = (int)floorf(fi) - 1;
        int j0 = (int)floorf(fj) - 1;

        float mx = 0.0f;
        #pragma unroll
        for (int di = 0; di < 4; ++di) {
            int i = i0 + di;
            i = i < 0 ? 0 : (i > 15 ? 15 : i);
            #pragma unroll
            for (int dj = 0; dj < 4; ++dj) {
                int j = (j0 + dj) & 31;
                int idx = i * 32 + j;
                mx = fmaxf(mx, fmaf(nx, shx[idx], fmaf(ny, shy[idx], nz * shz[idx])));
            }
        }
        #pragma unroll
        for (int di = 0; di < 3; ++di) {           // singular ring around (8,0)
            int i = 7 + di;
            #pragma unroll
            for (int dj = 0; dj < 5; ++dj) {
                int j = (30 + dj) & 31;
                int idx = i * 32 + j;
                mx = fmaxf(mx, fmaf(nx, shx[idx], fmaf(ny, shy[idx], nz * shz[idx])));
            }
        }

        #pragma unroll
        for (int off = 32; off > 0; off >>= 1)
            mx = fmaxf(mx, __shfl_xor(mx, off));
        if ((tid & 63) == 0) swmax[tid >> 6] = mx;
        __syncthreads();
        if (tid == 0)
            blockmax[mbid] = fmaxf(fmaxf(swmax[0], swmax[1]), fmaxf(swmax[2], swmax[3]));
    }
}

// ---------- Pass 2: in-block gmax reduce + bilinear lookup -> final output ----------
__global__ __launch_bounds__(256) void k_render(const float* __restrict__ normal,
                                                const float4* __restrict__ table,
                                                const float* __restrict__ blockmax,
                                                float* __restrict__ out) {
    __shared__ float sred[4];
    int tid = threadIdx.x, bid = blockIdx.x;
    int b = bid >> 10;
    int pix_in_b = (bid & 1023) * 256 + tid;

    // in-block reduction of the 2048 block maxes (L2-resident, 8 loads/thread;
    // same values, same order in every block -> bit-identical scale)
    float m = 0.0f;
    #pragma unroll
    for (int i = 0; i < NBLK / 256; ++i)
        m = fmaxf(m, blockmax[tid + i * 256]);

    float nx, ny, nz;
    load_normal(normal, (size_t)b * HWPX + pix_in_b, nx, ny, nz);

    #pragma unroll
    for (int off = 32; off > 0; off >>= 1)
        m = fmaxf(m, __shfl_xor(m, off));
    if ((tid & 63) == 0) sred[tid >> 6] = m;
    __syncthreads();
    m = fmaxf(fmaxf(sred[0], sred[1]), fmaxf(sred[2], sred[3]));
    float scl = pow64(1.0f / m);

    float phN = acos_fast(fminf(fmaxf(ny, -1.0f), 1.0f));
    float thN = atan2_fast(nx, -nz);
    float fiN = phN * ((float)NPH / PI_F);
    float tN  = thN * (0.5f / PI_F);
    float fjN = (tN - floorf(tN)) * (float)NTH;

    int iN = (int)fiN; iN = iN > (NPH - 1) ? (NPH - 1) : iN;
    int jN = (int)fjN; jN = jN > (NTH - 1) ? (NTH - 1) : jN;
    float wi = fiN - (float)iN;
    float wj = fjN - (float)jN;

    const float4* Tb = table + (size_t)b * NODESTRIDE;
    int idx = iN * COLS + jN;
    float4 t00 = Tb[idx];
    float4 t01 = Tb[idx + 1];
    float4 t10 = Tb[idx + COLS];
    float4 t11 = Tb[idx + COLS + 1];

    float w00 = (1.0f - wi) * (1.0f - wj);
    float w01 = (1.0f - wi) * wj;
    float w10 = wi * (1.0f - wj);
    float w11 = wi * wj;
    float r0 = t00.x * w00 + t01.x * w01 + t10.x * w10 + t11.x * w11;
    float r1 = t00.y * w00 + t01.y * w01 + t10.y * w10 + t11.y * w11;
    float r2 = t00.z * w00 + t01.z * w01 + t10.z * w10 + t11.z * w11;

    float* ob = out + (size_t)b * 3 * HWPX;
    ob[0 * HWPX + pix_in_b] = r0 * scl;
    ob[1 * HWPX + pix_in_b] = r1 * scl;
    ob[2 * HWPX + pix_in_b] = r2 * scl;
}

// ================= Fallback exact path (R13) for small ws =================
__global__ void k_setup_fb(const float* __restrict__ env,
                           float* __restrict__ tabq) {
    int m = threadIdx.x;
    int p = m >> 5;
    if (p < 1) return;
    float hx, hy, hz, sp;
    light_h(m, hx, hy, hz, sp);
    float c = sp * (1.0f / 60.0f);
    int ms = m - 32;
    int j = ms >> 1;
    int slot = ms & 1;
    #pragma unroll
    for (int b = 0; b < NB; ++b) {
        const float* e = env + ((size_t)(b * NL + m)) * 3;
        float* dst = tabq + ((size_t)(b * NPAIR + j)) * 12 + slot;
        dst[0]  = hx;
        dst[2]  = hy;
        dst[4]  = hz;
        dst[6]  = e[0] * c;
        dst[8]  = e[1] * c;
        dst[10] = e[2] * c;
    }
}

__global__ __launch_bounds__(256) void k_fused_fb(const float* __restrict__ normal,
                                                  const float* __restrict__ tabq,
                                                  float* __restrict__ out,
                                                  float* __restrict__ blockmax) {
    __shared__ float smerge[3 * 64 * 13];
    __shared__ float swmax[4];
    int tid = threadIdx.x, bid = blockIdx.x;
    int bpb = HWPX / 256;
    int b = bid / bpb;
    int g = tid >> 6;
    int li = tid & 63;
    int base_in_b = (bid % bpb) * 256 + li;
    int toff = __builtin_amdgcn_readfirstlane((b * NPAIR + g * GPAIR) * 12);
    const float* Tw = tabq + toff;

    float nxs[4], nys[4], nzs[4];
    #pragma unroll
    for (int k = 0; k < 4; ++k)
        load_normal(normal, (size_t)b * HWPX + base_in_b + k * 64, nxs[k], nys[k], nzs[k]);
    f2 nx2[4], ny2[4], nz2[4];
    #pragma unroll
    for (int k = 0; k < 4; ++k) {
        nx2[k] = f2{nxs[k], nxs[k]};
        ny2[k] = f2{nys[k], nys[k]};
        nz2[k] = f2{nzs[k], nzs[k]};
    }
    float mx64 = 0.0f;
    if (g == 0) {
        #pragma unroll
        for (int k = 0; k < 4; ++k) {
            float s0 = fmaxf((nys[k] + nzs[k]) * INV_SQRT2, 0.0f);
            mx64 = fmaxf(mx64, pow64(s0));
        }
    }
    f2 a0[4], a1[4], a2[4];
    #pragma unroll
    for (int k = 0; k < 4; ++k) { a0[k] = f2{0,0}; a1[k] = f2{0,0}; a2[k] = f2{0,0}; }
    #pragma unroll 4
    for (int j = 0; j < GPAIR; ++j) {
        const f2* P = reinterpret_cast<const f2*>(Tw + j * 12);
        f2 hx2 = P[0], hy2 = P[1], hz2 = P[2];
        f2 e02 = P[3], e12 = P[4], e22 = P[5];
        #pragma unroll
        for (int k = 0; k < 4; ++k) {
            f2 s = __builtin_elementwise_fma(nx2[k], hx2,
                   __builtin_elementwise_fma(ny2[k], hy2, nz2[k] * hz2));
            float sx = fmaxf(s.x, 0.0f);
            float sy = fmaxf(s.y, 0.0f);
            f2 r = {sx, sy};
            f2 r2  = r * r;
            f2 r4  = r2 * r2;
            f2 r8  = r4 * r4;
            f2 r16 = r8 * r8;
            f2 r32 = r16 * r16;
            f2 r64 = r32 * r32;
            mx64 = fmaxf(mx64, fmaxf(r64.x, r64.y));
            a0[k] = __builtin_elementwise_fma(r64, e02, a0[k]);
            a1[k] = __builtin_elementwise_fma(r64, e12, a1[k]);
            a2[k] = __builtin_elementwise_fma(r64, e22, a2[k]);
        }
    }
    float b0[4], b1[4], b2[4];
    #pragma unroll
    for (int k = 0; k < 4; ++k) {
        b0[k] = a0[k].x + a0[k].y;
        b1[k] = a1[k].x + a1[k].y;
        b2[k] = a2[k].x + a2[k].y;
    }
    #pragma unroll
    for (int off = 32; off > 0; off >>= 1)
        mx64 = fmaxf(mx64, __shfl_xor(mx64, off));
    if (li == 0) swmax[g] = mx64;
    if (g > 0) {
        float* dst = smerge + (size_t)(g - 1) * (64 * 13) + li * 13;
        #pragma unroll
        for (int k = 0; k < 4; ++k) {
            dst[k] = b0[k]; dst[k + 4] = b1[k]; dst[k + 8] = b2[k];
        }
    }
    __syncthreads();
    if (tid == 0)
        blockmax[bid] = fmaxf(fmaxf(swmax[0], swmax[1]), fmaxf(swmax[2], swmax[3]));
    if (g == 0) {
        #pragma unroll
        for (int gg = 0; gg < 3; ++gg) {
            const float* src = smerge + (size_t)gg * (64 * 13) + li * 13;
            #pragma unroll
            for (int k = 0; k < 4; ++k) {
                b0[k] += src[k]; b1[k] += src[k + 4]; b2[k] += src[k + 8];
            }
        }
        float* ob = out + (size_t)b * 3 * HWPX;
        #pragma unroll
        for (int k = 0; k < 4; ++k) {
            int p = base_in_b + k * 64;
            ob[0 * HWPX + p] = b0[k];
            ob[1 * HWPX + p] = b1[k];
            ob[2 * HWPX + p] = b2[k];
        }
    }
}

__global__ __launch_bounds__(256) void k_gmax_inv(const float* __restrict__ blockmax,
                                                  float* __restrict__ scale) {
    __shared__ float sm[4];
    int t = threadIdx.x;
    float m = 0.0f;
    #pragma unroll
    for (int i = 0; i < NBLK / 256; ++i)
        m = fmaxf(m, blockmax[t + i * 256]);
    #pragma unroll
    for (int off = 32; off > 0; off >>= 1)
        m = fmaxf(m, __shfl_xor(m, off));
    if ((t & 63) == 0) sm[t >> 6] = m;
    __syncthreads();
    if (t == 0) {
        m = fmaxf(fmaxf(sm[0], sm[1]), fmaxf(sm[2], sm[3]));
        *scale = 1.0f / m;
    }
}

__global__ __launch_bounds__(256) void k_finalize_fb(float* __restrict__ out,
                                                     const float* __restrict__ scale) {
    float scl = *scale;
    int i = blockIdx.x * 256 + (int)threadIdx.x;
    float4* o = reinterpret_cast<float4*>(out);
    float4 v = o[i];
    v.x *= scl; v.y *= scl; v.z *= scl; v.w *= scl;
    o[i] = v;
}

extern "C" void kernel_launch(void* const* d_in, const int* in_sizes, int n_in,
                              void* d_out, int out_size, void* d_ws, size_t ws_size,
                              hipStream_t stream) {
    const float* env    = (const float*)d_in[0];   // (B,16,32,3) f32
    const float* normal = (const float*)d_in[1];   // (B,512,512,3) f32
    float* out = (float*)d_out;                    // (B,3,512,512) f32

    char* ws = (char*)d_ws;

    size_t need = 16384 + (size_t)NB * NODESTRIDE * 16;   // ~280 KB

    if (ws_size >= need) {
        float* blockmax = (float*)(ws + 256);
        float4* table = (float4*)(ws + 16384);
        hipLaunchKernelGGL(k_pre, dim3(NBUILD + NBLK), dim3(256), 0, stream,
                           env, normal, table, blockmax);
        hipLaunchKernelGGL(k_render, dim3(NBLK), dim3(256), 0, stream,
                           normal, table, blockmax, out);
    } else {
        float* scale = (float*)ws;
        float* tabq = (float*)(ws + 256);
        float* blockmax = (float*)(ws + 24576);
        int fblocks = (NB * 3 * HWPX) / (4 * 256);
        hipLaunchKernelGGL(k_setup_fb, dim3(1), dim3(NL), 0, stream, env, tabq);
        hipLaunchKernelGGL(k_fused_fb, dim3(NBLK), dim3(256), 0, stream, normal, tabq, out, blockmax);
        hipLaunchKernelGGL(k_gmax_inv, dim3(1), dim3(256), 0, stream, blockmax, scale);
        hipLaunchKernelGGL(k_finalize_fb, dim3(fblocks), dim3(256), 0, stream, out, scale);
    }
}